// Round 11
// baseline (774.219 us; speedup 1.0000x reference)
//
#include <hip/hip_runtime.h>
#include <cmath>

// ---------------------------------------------------------------------------
// GraphTransformer on MI355X.  N=8192, D=128, k=7, OUT=1.
// Attention: split-bf16 (hi/lo) MFMA flash, fixed max (logits bounded).
//   QK^T MUST stay 3-term split: round-10 (plain-bf16 QK) flipped a kNN
//   neighbor (dS~0.02 -> dH~1e-5; passing window is dH<~2e-6).
//   NO register prefetch (round-8: spills, WRITE_SIZE 33->71MB).
//   VSTR/PSTR=34 (17 words, odd -> bank-clean) shrinks LDS to 52.2KB
//   -> 3 blocks/CU for barrier-drain overlap.
// kNN: swapped-operand bf16 MFMA, per-lane register top-10 (u32-packed),
// in-kernel lq-merge -> candV, parallel final merge, exact fp32 re-rank.
// GCN tail: fp32 VALU, gather1+m2 fused.
// ---------------------------------------------------------------------------

typedef unsigned short ushort_t;

constexpr int   NN    = 8192;
constexpr int   DD    = 128;
constexpr int   KNB   = 7;
constexpr int   NL    = 10;              // per-lane kept candidates (knn)
constexpr int   NCAND = 12;              // merged candidates per node
constexpr float SCALE = 0.088388347648318447f;   // 1/sqrt(128)

using bf16x8 = __attribute__((ext_vector_type(8))) short;   // 8 bf16 = 4 VGPR
using f32x4  = __attribute__((ext_vector_type(4))) float;   // mfma acc

#define MFMA16(a, b, c) __builtin_amdgcn_mfma_f32_16x16x32_bf16((a), (b), (c), 0, 0, 0)

__device__ __forceinline__ ushort_t f2b(float f) {
    union { float f; unsigned int u; } v; v.f = f;
    return (ushort_t)((v.u + 0x8000u) >> 16);
}
__device__ __forceinline__ float b2f(ushort_t h) {
    union { unsigned int u; float f; } v; v.u = ((unsigned int)h) << 16;
    return v.f;
}

// u32 (d2-bits-truncated | idx13) top-K insert; valid because d2 > 0.
template<int K>
__device__ __forceinline__ void topk_insert_u32(unsigned* bk, unsigned key)
{
    if (key < bk[0]) {
        bool placed = false;
        #pragma unroll
        for (int p = 0; p < K - 1; ++p) {
            const unsigned nxt = bk[p + 1];
            const bool sh = (!placed) && (key < nxt);
            if (!placed) bk[p] = sh ? nxt : key;
            placed = placed || !sh;
        }
        if (!placed) bk[K - 1] = key;
    }
}

// ---------------- projections: Q,K (split bf16), V (f32), skip (f32) -------
__global__ __launch_bounds__(128)
void proj_kernel(const float* __restrict__ x,
                 const float* __restrict__ Wq, const float* __restrict__ bq,
                 const float* __restrict__ Wk, const float* __restrict__ bk,
                 const float* __restrict__ Wv, const float* __restrict__ bv,
                 const float* __restrict__ Ws, const float* __restrict__ bs,
                 ushort_t* __restrict__ Qhi, ushort_t* __restrict__ Qlo,
                 ushort_t* __restrict__ Khi, ushort_t* __restrict__ Klo,
                 float* __restrict__ Vf, float* __restrict__ HS)
{
    __shared__ float xs[4][DD];
    const int i0 = blockIdx.x * 4, t = threadIdx.x;
    #pragma unroll
    for (int r = 0; r < 4; ++r) xs[r][t] = x[(i0 + r) * DD + t];
    __syncthreads();
    float aq[4] = {0,0,0,0}, ak[4] = {0,0,0,0}, av[4] = {0,0,0,0}, ah[4] = {0,0,0,0};
    #pragma unroll 4
    for (int c = 0; c < DD; ++c) {
        const float wq = Wq[c * DD + t], wk = Wk[c * DD + t];
        const float wv = Wv[c * DD + t], ws = Ws[c * DD + t];
        #pragma unroll
        for (int r = 0; r < 4; ++r) {
            const float xv = xs[r][c];
            aq[r] = fmaf(xv, wq, aq[r]); ak[r] = fmaf(xv, wk, ak[r]);
            av[r] = fmaf(xv, wv, av[r]); ah[r] = fmaf(xv, ws, ah[r]);
        }
    }
    #pragma unroll
    for (int r = 0; r < 4; ++r) {
        const int o = (i0 + r) * DD + t;
        const float q = aq[r] + bq[t];
        const float k = ak[r] + bk[t];
        const ushort_t qh = f2b(q); Qhi[o] = qh; Qlo[o] = f2b(q - b2f(qh));
        const ushort_t kh = f2b(k); Khi[o] = kh; Klo[o] = f2b(k - b2f(kh));
        Vf[o] = av[r] + bv[t];
        HS[o] = ah[r] + bs[t];
    }
}

// ---------------- V transpose + split: VT{hi,lo}[f][n] = split(V[n][f]) ----
__global__ __launch_bounds__(256)
void vt_kernel(const float* __restrict__ Vf,
               ushort_t* __restrict__ VThi, ushort_t* __restrict__ VTlo)
{
    __shared__ float tile[64 * 132];
    const int k0 = blockIdx.x * 64, t = threadIdx.x;
    #pragma unroll
    for (int p = 0; p < 8; ++p) {
        const int slot = t + p * 256;        // 2048 slots: 64 rows x 32 f4-chunks
        const int r = slot >> 5, c4 = slot & 31;
        *reinterpret_cast<float4*>(&tile[r * 132 + c4 * 4]) =
            *reinterpret_cast<const float4*>(Vf + (k0 + r) * DD + c4 * 4);
    }
    __syncthreads();
    #pragma unroll
    for (int p = 0; p < 4; ++p) {
        const int slot = t + p * 256;        // 1024 slots: 128 feats x 8 chunks
        const int f = slot >> 3, kc = slot & 7;
        ushort_t hh[8], ll[8];
        #pragma unroll
        for (int i = 0; i < 8; ++i) {
            const float v = tile[(kc * 8 + i) * 132 + f];
            hh[i] = f2b(v); ll[i] = f2b(v - b2f(hh[i]));
        }
        *reinterpret_cast<uint4*>(VThi + f * NN + k0 + kc * 8) =
            *reinterpret_cast<const uint4*>(hh);
        *reinterpret_cast<uint4*>(VTlo + f * NN + k0 + kc * 8) =
            *reinterpret_cast<const uint4*>(ll);
    }
}

// ---------------- split-bf16 MFMA flash attention, fixed max ---------------
constexpr int ANS  = 8;                 // key slices
constexpr int AKS  = NN / ANS;          // 1024 keys per slice
constexpr int BK   = 32;                // keys per tile
constexpr int KSTR = 136;               // K row stride (bf16): <=2-way banks
constexpr int VSTR = 34;                // VT row stride (17 words, odd)
constexpr int PSTR = 34;

__global__ __launch_bounds__(256, 3)
void attn_kernel(const ushort_t* __restrict__ Qhi, const ushort_t* __restrict__ Qlo,
                 const ushort_t* __restrict__ Khg, const ushort_t* __restrict__ Klg,
                 const ushort_t* __restrict__ Vhg, const ushort_t* __restrict__ Vlg,
                 float* __restrict__ Opart, float* __restrict__ lpart)
{
    __shared__ __align__(16) ushort_t Khs[BK * KSTR];
    __shared__ __align__(16) ushort_t Kls[BK * KSTR];
    __shared__ __align__(16) ushort_t Vhs[128 * VSTR];
    __shared__ __align__(16) ushort_t Vls[128 * VSTR];
    __shared__ __align__(16) ushort_t Phs[4 * 32 * PSTR];
    __shared__ __align__(16) ushort_t Pls[4 * 32 * PSTR];

    const int t  = threadIdx.x;
    const int w  = t >> 6, l = t & 63;
    const int lc = l & 15, lq = l >> 4;
    const int b  = blockIdx.x;
    const int s  = b >> 6;              // slice 0..7
    const int qb = b & 63;
    const int i0 = qb * 128;
    const int k0 = s * AKS;
    ushort_t* Pwh = Phs + w * 32 * PSTR;
    ushort_t* Pwl = Pls + w * 32 * PSTR;

    bf16x8 qh[2][4], ql[2][4];
    #pragma unroll
    for (int sub = 0; sub < 2; ++sub) {
        const int row = i0 + w * 32 + sub * 16 + lc;
        #pragma unroll
        for (int kb = 0; kb < 4; ++kb) {
            qh[sub][kb] = *reinterpret_cast<const bf16x8*>(Qhi + row * DD + kb * 32 + lq * 8);
            ql[sub][kb] = *reinterpret_cast<const bf16x8*>(Qlo + row * DD + kb * 32 + lq * 8);
        }
    }

    const f32x4 zz = {0.f, 0.f, 0.f, 0.f};
    f32x4 oacc[2][8];
    #pragma unroll
    for (int sub = 0; sub < 2; ++sub)
        #pragma unroll
        for (int ft = 0; ft < 8; ++ft) oacc[sub][ft] = zz;
    float lrow[2][4];
    #pragma unroll
    for (int sub = 0; sub < 2; ++sub)
        #pragma unroll
        for (int r = 0; r < 4; ++r) lrow[sub][r] = 0.f;

    for (int jt0 = 0; jt0 < AKS; jt0 += BK) {
        const int jt = k0 + jt0;
        __syncthreads();
        #pragma unroll
        for (int p = 0; p < 2; ++p) {       // K tiles 32x128 (hi+lo)
            const int slot = t + p * 256;
            const int r = slot >> 4, c = slot & 15;
            *reinterpret_cast<uint4*>(&Khs[r * KSTR + c * 8]) =
                *reinterpret_cast<const uint4*>(Khg + (jt + r) * DD + c * 8);
            *reinterpret_cast<uint4*>(&Kls[r * KSTR + c * 8]) =
                *reinterpret_cast<const uint4*>(Klg + (jt + r) * DD + c * 8);
        }
        #pragma unroll
        for (int p = 0; p < 2; ++p) {       // VT tiles 128x32 (hi+lo)
            const int slot = t + p * 256;
            const int f = slot >> 2, c = slot & 3;
            *reinterpret_cast<uint4*>(&Vhs[f * VSTR + c * 8]) =
                *reinterpret_cast<const uint4*>(Vhg + f * NN + jt + c * 8);
            *reinterpret_cast<uint4*>(&Vls[f * VSTR + c * 8]) =
                *reinterpret_cast<const uint4*>(Vlg + f * NN + jt + c * 8);
        }
        __syncthreads();

        // ---- S = Q K^T, split: qh*kh + ql*kh + qh*kl ----
        f32x4 sacc[2][2];
        #pragma unroll
        for (int sub = 0; sub < 2; ++sub)
            #pragma unroll
            for (int ct = 0; ct < 2; ++ct) sacc[sub][ct] = zz;
        #pragma unroll
        for (int ct = 0; ct < 2; ++ct) {
            #pragma unroll
            for (int kb = 0; kb < 4; ++kb) {
                const bf16x8 kh = *reinterpret_cast<const bf16x8*>(
                    &Khs[(ct * 16 + lc) * KSTR + kb * 32 + lq * 8]);
                const bf16x8 kl = *reinterpret_cast<const bf16x8*>(
                    &Kls[(ct * 16 + lc) * KSTR + kb * 32 + lq * 8]);
                #pragma unroll
                for (int sub = 0; sub < 2; ++sub) {
                    sacc[sub][ct] = MFMA16(qh[sub][kb], kh, sacc[sub][ct]);
                    sacc[sub][ct] = MFMA16(ql[sub][kb], kh, sacc[sub][ct]);
                    sacc[sub][ct] = MFMA16(qh[sub][kb], kl, sacc[sub][ct]);
                }
            }
        }
        if ((jt & ~127) == i0) {            // diagonal mask
            #pragma unroll
            for (int sub = 0; sub < 2; ++sub)
                #pragma unroll
                for (int ct = 0; ct < 2; ++ct) {
                    const int gk = jt + ct * 16 + lc;
                    #pragma unroll
                    for (int r = 0; r < 4; ++r) {
                        const int gq = i0 + w * 32 + sub * 16 + lq * 4 + r;
                        if (gk == gq) sacc[sub][ct][r] = -INFINITY;
                    }
                }
        }
        // ---- P = exp(S*SCALE), split to LDS ----
        #pragma unroll
        for (int sub = 0; sub < 2; ++sub)
            #pragma unroll
            for (int ct = 0; ct < 2; ++ct)
                #pragma unroll
                for (int r = 0; r < 4; ++r) {
                    const float p = __expf(sacc[sub][ct][r] * SCALE);
                    lrow[sub][r] += p;
                    const ushort_t ph = f2b(p);
                    const int off = (sub * 16 + lq * 4 + r) * PSTR + ct * 16 + lc;
                    Pwh[off] = ph;
                    Pwl[off] = f2b(p - b2f(ph));
                }
        bf16x8 pfh[2], pfl[2];
        #pragma unroll
        for (int sub = 0; sub < 2; ++sub) {
            pfh[sub] = *reinterpret_cast<const bf16x8*>(&Pwh[(sub * 16 + lc) * PSTR + lq * 8]);
            pfl[sub] = *reinterpret_cast<const bf16x8*>(&Pwl[(sub * 16 + lc) * PSTR + lq * 8]);
        }
        // ---- O += P V, split: ph*vh + pl*vh + ph*vl ----
        #pragma unroll
        for (int ft = 0; ft < 8; ++ft) {
            const bf16x8 vh = *reinterpret_cast<const bf16x8*>(
                &Vhs[(ft * 16 + lc) * VSTR + lq * 8]);
            const bf16x8 vl = *reinterpret_cast<const bf16x8*>(
                &Vls[(ft * 16 + lc) * VSTR + lq * 8]);
            #pragma unroll
            for (int sub = 0; sub < 2; ++sub) {
                oacc[sub][ft] = MFMA16(pfh[sub], vh, oacc[sub][ft]);
                oacc[sub][ft] = MFMA16(pfl[sub], vh, oacc[sub][ft]);
                oacc[sub][ft] = MFMA16(pfh[sub], vl, oacc[sub][ft]);
            }
        }
    }

    #pragma unroll
    for (int sub = 0; sub < 2; ++sub) {
        #pragma unroll
        for (int r = 0; r < 4; ++r) {
            float ps = lrow[sub][r];
            ps += __shfl_xor(ps, 1, 64);
            ps += __shfl_xor(ps, 2, 64);
            ps += __shfl_xor(ps, 4, 64);
            ps += __shfl_xor(ps, 8, 64);
            lrow[sub][r] = ps;
        }
        #pragma unroll
        for (int r = 0; r < 4; ++r) {
            const int row = i0 + w * 32 + sub * 16 + lq * 4 + r;
            float* po = Opart + ((size_t)s * NN + row) * DD;
            #pragma unroll
            for (int ft = 0; ft < 8; ++ft) po[ft * 16 + lc] = oacc[sub][ft][r];
        }
        if (lc == 0) {
            #pragma unroll
            for (int r = 0; r < 4; ++r) {
                const int row = i0 + w * 32 + sub * 16 + lq * 4 + r;
                lpart[s * NN + row] = lrow[sub][r];
            }
        }
    }
}

// ------- merge slices + skip, emit H (in-place over HS), Hhi, SQ -----------
__global__ __launch_bounds__(256)
void attn_merge_kernel(const float* __restrict__ Opart, const float* __restrict__ lpart,
                       const float* __restrict__ HS, float* __restrict__ H,
                       ushort_t* __restrict__ Hhi, float* __restrict__ SQ)
{
    __shared__ float red[256];
    const int t = threadIdx.x;
    const int gid = blockIdx.x * 256 + t;
    const int i = gid >> 7, f = gid & 127;
    float ls = 0.f, o = 0.f;
    #pragma unroll
    for (int s = 0; s < ANS; ++s) {
        ls += lpart[s * NN + i];
        o  += Opart[((size_t)s * NN + i) * DD + f];
    }
    const float h = o / ls + HS[i * DD + f];
    H[i * DD + f]   = h;
    Hhi[i * DD + f] = f2b(h);
    red[t] = h * h;
    __syncthreads();
    for (int s2 = 64; s2 > 0; s2 >>= 1) {
        if ((t & 127) < s2) red[t] += red[t + s2];
        __syncthreads();
    }
    if ((t & 127) == 0) SQ[i] = red[t];
}

// ---------------- kNN: swapped-operand MFMA, register top-NL (u32) ---------
constexpr int KNSL = 16;                // key slices (512 keys each)
constexpr int KSL  = NN / KNSL;         // 512

__global__ __launch_bounds__(256, 4)
void knn_kernel(const ushort_t* __restrict__ Hhi, const float* __restrict__ SQg,
                unsigned* __restrict__ candV)
{
    __shared__ __align__(16) ushort_t Khi[64 * KSTR];
    __shared__ __align__(16) float sqs[64];

    const int t  = threadIdx.x;
    const int w  = t >> 6, l = t & 63;
    const int lc = l & 15, lq = l >> 4;
    const int b  = blockIdx.x;
    const int s  = b >> 6;              // slice 0..15
    const int qb = b & 63;
    const int i0 = qb * 128;
    const int k0 = s * KSL;

    const int kr = t >> 4, kc2 = t & 15;   // staging coords (4 chunks of 16 rows)

    const int gq0 = i0 + w * 32 + lc;          // sub=0 query
    const int gq1 = gq0 + 16;                  // sub=1 query
    const float sqi0 = SQg[gq0];
    const float sqi1 = SQg[gq1];

    bf16x8 qf[2][4];                    // B operand: B[n=query=lc][k=lq*8+j]
    #pragma unroll
    for (int sub = 0; sub < 2; ++sub) {
        const int row = i0 + w * 32 + sub * 16 + lc;
        #pragma unroll
        for (int kb = 0; kb < 4; ++kb)
            qf[sub][kb] = *reinterpret_cast<const bf16x8*>(Hhi + row * DD + kb * 32 + lq * 8);
    }

    unsigned lists[2][NL];
    #pragma unroll
    for (int sub = 0; sub < 2; ++sub)
        #pragma unroll
        for (int p = 0; p < NL; ++p) lists[sub][p] = 0xFFFFFFFFu;

    // prefetch tile 0 (knn has VGPR headroom, no spill at 4 waves/EU)
    uint4 pk[4]; float psq;
    #pragma unroll
    for (int p = 0; p < 4; ++p)
        pk[p] = *reinterpret_cast<const uint4*>(Hhi + (k0 + kr + p * 16) * DD + kc2 * 8);
    psq = (t < 64) ? SQg[k0 + t] : 0.f;

    const f32x4 zz = {0.f, 0.f, 0.f, 0.f};
    for (int jt0 = 0; jt0 < KSL; jt0 += 64) {
        const int jt = k0 + jt0;
        __syncthreads();                 // prev K-frag reads done
        #pragma unroll
        for (int p = 0; p < 4; ++p)
            *reinterpret_cast<uint4*>(&Khi[(kr + p * 16) * KSTR + kc2 * 8]) = pk[p];
        if (t < 64) sqs[t] = psq;
        __syncthreads();
        if (jt0 + 64 < KSL) {            // prefetch next during compute
            const int jn = jt + 64;
            #pragma unroll
            for (int p = 0; p < 4; ++p)
                pk[p] = *reinterpret_cast<const uint4*>(Hhi + (jn + kr + p * 16) * DD + kc2 * 8);
            psq = (t < 64) ? SQg[jn + t] : 0.f;
        }

        f32x4 acc[2][4];                 // [sub][kt]
        #pragma unroll
        for (int sub = 0; sub < 2; ++sub)
            #pragma unroll
            for (int kt = 0; kt < 4; ++kt) acc[sub][kt] = zz;
        #pragma unroll
        for (int kt = 0; kt < 4; ++kt) {
            #pragma unroll
            for (int kb = 0; kb < 4; ++kb) {
                const bf16x8 kf = *reinterpret_cast<const bf16x8*>(
                    &Khi[(kt * 16 + lc) * KSTR + kb * 32 + lq * 8]);
                acc[0][kt] = MFMA16(kf, qf[0][kb], acc[0][kt]);   // A=key, B=query
                acc[1][kt] = MFMA16(kf, qf[1][kb], acc[1][kt]);
            }
        }

        const bool ovl = ((jt & ~127) == i0);
        #pragma unroll
        for (int kt = 0; kt < 4; ++kt) {
            const float4 sq4 = *reinterpret_cast<const float4*>(&sqs[kt * 16 + lq * 4]);
            const float sqj[4] = {sq4.x, sq4.y, sq4.z, sq4.w};
            #pragma unroll
            for (int r = 0; r < 4; ++r) {
                const int gk = jt + kt * 16 + lq * 4 + r;
                float d0 = fmaf(-2.f, acc[0][kt][r], sqi0 + sqj[r]);
                float d1 = fmaf(-2.f, acc[1][kt][r], sqi1 + sqj[r]);
                if (ovl) {
                    if (gk == gq0) d0 = INFINITY;
                    if (gk == gq1) d1 = INFINITY;
                }
                const unsigned u0 = (__float_as_uint(d0) & 0xFFFFE000u) | (unsigned)gk;
                const unsigned u1 = (__float_as_uint(d1) & 0xFFFFE000u) | (unsigned)gk;
                topk_insert_u32<NL>(lists[0], u0);
                topk_insert_u32<NL>(lists[1], u1);
            }
        }
    }

    // ---- in-kernel lq-merge: Khi is dead, reuse as scratch ----
    __syncthreads();                     // all waves done with Khi MFMA reads
    unsigned* msw = reinterpret_cast<unsigned*>(Khi) + w * (16 * 4 * NL);
    #pragma unroll
    for (int sub = 0; sub < 2; ++sub) {
        #pragma unroll
        for (int p = 0; p < NL; ++p)
            msw[lc * (4 * NL) + lq * NL + p] = lists[sub][p];
        __syncthreads();
        if (lq == 0) {                   // 16 lanes/wave: one query each
            unsigned bk[NL];
            #pragma unroll
            for (int p = 0; p < NL; ++p) bk[p] = msw[lc * (4 * NL) + p];
            #pragma unroll
            for (int o = 1; o < 4; ++o)
                #pragma unroll
                for (int e = 0; e < NL; ++e)
                    topk_insert_u32<NL>(bk, msw[lc * (4 * NL) + o * NL + e]);
            const int node = i0 + w * 32 + sub * 16 + lc;
            #pragma unroll
            for (int p = 0; p < NL; ++p)
                candV[((size_t)s * NL + p) * NN + node] = bk[p];
        }
        __syncthreads();
    }
}

// ------- final merge: 16 slice lists -> top-12 candidates per node ---------
__global__ __launch_bounds__(64)
void knn_merge_kernel(const unsigned* __restrict__ candV, int* __restrict__ CAND)
{
    const int q = blockIdx.x * 64 + threadIdx.x;
    unsigned bk[NCAND];
    #pragma unroll
    for (int p = 0; p < NCAND; ++p) bk[p] = 0xFFFFFFFFu;
    for (int s = 0; s < KNSL; ++s)
        #pragma unroll
        for (int e = 0; e < NL; ++e)
            topk_insert_u32<NCAND>(bk, candV[((size_t)s * NL + e) * NN + q]);
    #pragma unroll
    for (int p = 0; p < NCAND; ++p)
        CAND[q * NCAND + p] = (int)(bk[p] & 8191u);
}

// ---------------- exact fp32 re-rank of candidates -> IDX ----------------
__global__ __launch_bounds__(256)
void rerank_kernel(const float* __restrict__ H, const float* __restrict__ SQ,
                   const int* __restrict__ CAND, int* __restrict__ IDX)
{
    const int t = threadIdx.x;
    const int w = t >> 6, l = t & 63;
    const int node = blockIdx.x * 4 + w;
    const float h0 = H[node * DD + l];
    const float h1 = H[node * DD + 64 + l];
    float dk[NCAND]; int di[NCAND];
    #pragma unroll
    for (int c = 0; c < NCAND; ++c) {
        const int j = CAND[node * NCAND + c];
        float p = h0 * H[j * DD + l] + h1 * H[j * DD + 64 + l];
        p += __shfl_xor(p, 1, 64);
        p += __shfl_xor(p, 2, 64);
        p += __shfl_xor(p, 4, 64);
        p += __shfl_xor(p, 8, 64);
        p += __shfl_xor(p, 16, 64);
        p += __shfl_xor(p, 32, 64);
        dk[c] = SQ[j] - 2.f * p;
        di[c] = j;
    }
    if (l == 0) {
        #pragma unroll
        for (int s = 0; s < KNB; ++s) {
            int best = s;
            #pragma unroll
            for (int c = s + 1; c < NCAND; ++c) {
                const bool lt = (dk[c] < dk[best]) ||
                                (dk[c] == dk[best] && di[c] < di[best]);
                if (lt) best = c;
            }
            const float tk = dk[s]; dk[s] = dk[best]; dk[best] = tk;
            const int   ti = di[s]; di[s] = di[best]; di[best] = ti;
            IDX[node * KNB + s] = di[s];
        }
    }
}

// ---------------- M1 = H @ W1 (f32, 4 rows/block) ----------------
__global__ __launch_bounds__(128)
void mat1_kernel(const float* __restrict__ Hin, const float* __restrict__ W,
                 float* __restrict__ M)
{
    __shared__ float xs[4][DD];
    const int i0 = blockIdx.x * 4, t = threadIdx.x;
    #pragma unroll
    for (int r = 0; r < 4; ++r) xs[r][t] = Hin[(i0 + r) * DD + t];
    __syncthreads();
    float a[4] = {0,0,0,0};
    #pragma unroll 4
    for (int c = 0; c < DD; ++c) {
        const float wv = W[c * DD + t];
        #pragma unroll
        for (int r = 0; r < 4; ++r) a[r] = fmaf(xs[r][c], wv, a[r]);
    }
    #pragma unroll
    for (int r = 0; r < 4; ++r) M[(i0 + r) * DD + t] = a[r];
}

// -------- fused: H1 = relu((sum_nbr M1 + M1)/8 + b1); M2 = H1.W2 ----------
__global__ __launch_bounds__(128)
void g1m2_kernel(const float* __restrict__ M1, const int* __restrict__ IDX,
                 const float* __restrict__ b1, const float* __restrict__ W2,
                 float* __restrict__ M2)
{
    __shared__ float red[128];
    const int i = blockIdx.x, t = threadIdx.x;
    float s = M1[i * DD + t];
    #pragma unroll
    for (int p = 0; p < KNB; ++p) s += M1[IDX[i * KNB + p] * DD + t];
    const float h1 = fmaxf(s * 0.125f + b1[t], 0.f);
    red[t] = h1 * W2[t];
    __syncthreads();
    for (int s2 = 64; s2 > 0; s2 >>= 1) {
        if (t < s2) red[t] += red[t + s2];
        __syncthreads();
    }
    if (t == 0) M2[i] = red[0];
}

// ---------------- out = (sum_nbr M2 + M2)/8 + b2 ----------------
__global__ __launch_bounds__(256)
void out_kernel(const float* __restrict__ M2, const int* __restrict__ IDX,
                const float* __restrict__ b2, float* __restrict__ out)
{
    const int i = blockIdx.x * 256 + threadIdx.x;
    if (i < NN) {
        float s = M2[i];
        #pragma unroll
        for (int p = 0; p < KNB; ++p) s += M2[IDX[i * KNB + p]];
        out[i] = s * 0.125f + b2[0];
    }
}

// ---------------------------------------------------------------------------
extern "C" void kernel_launch(void* const* d_in, const int* in_sizes, int n_in,
                              void* d_out, int out_size, void* d_ws, size_t ws_size,
                              hipStream_t stream)
{
    const float* x   = (const float*)d_in[0];
    const float* Wq  = (const float*)d_in[1];
    const float* bq  = (const float*)d_in[2];
    const float* Wk  = (const float*)d_in[3];
    const float* bk  = (const float*)d_in[4];
    const float* Wv  = (const float*)d_in[5];
    const float* bv  = (const float*)d_in[6];
    const float* Wsk = (const float*)d_in[7];
    const float* bsk = (const float*)d_in[8];
    const float* W1  = (const float*)d_in[9];
    const float* b1  = (const float*)d_in[10];
    const float* W2  = (const float*)d_in[11];
    const float* b2  = (const float*)d_in[12];

    constexpr size_t MB = 1024 * 1024;
    char* W = (char*)d_ws;
    // persistent: [0,8) Q/K splits, [8,12) VT splits, [12,16) HS (->H in place)
    ushort_t* Qhi  = (ushort_t*)(W + 0 * MB);
    ushort_t* Qlo  = (ushort_t*)(W + 2 * MB);
    ushort_t* Khi  = (ushort_t*)(W + 4 * MB);
    ushort_t* Klo  = (ushort_t*)(W + 6 * MB);
    ushort_t* VThi = (ushort_t*)(W + 8 * MB);
    ushort_t* VTlo = (ushort_t*)(W + 10 * MB);
    float*    HS   = (float*)(W + 12 * MB);
    float*    H    = HS;                                   // in-place merge
    ushort_t* Hhi  = Qhi;            // Q dead after attn; Hhi written by merge
    // small: [16,17)
    float* lpart = (float*)(W + 16 * MB);                  // 256KB
    float* SQ    = (float*)(W + 16 * MB + 256 * 1024);     // 32KB
    float* M2    = SQ + NN;                                // 32KB
    int*   IDX   = (int*)(M2 + NN);                        // 224KB
    // union: [17,49):
    //   Vf32  [17,21)   dead after vt
    //   Opart [17,49)   dead after attn_merge
    //   candV [17,22.25) written by knn, dead after knn_merge (5.25MB)
    //   CAND  [23,23.4) written by knn_merge, dead after rerank
    //   M1    [24,28)   written by mat1
    float*    Vf32  = (float*)(W + 17 * MB);
    float*    Opart = (float*)(W + 17 * MB);
    unsigned* candV = (unsigned*)(W + 17 * MB);
    int*      CAND  = (int*)(W + 23 * MB);
    float*    M1    = (float*)(W + 24 * MB);

    proj_kernel<<<NN / 4, 128, 0, stream>>>(x, Wq, bq, Wk, bk, Wv, bv, Wsk, bsk,
                                            Qhi, Qlo, Khi, Klo, Vf32, HS);
    vt_kernel<<<NN / 64, 256, 0, stream>>>(Vf32, VThi, VTlo);
    attn_kernel<<<ANS * 64, 256, 0, stream>>>(Qhi, Qlo, Khi, Klo, VThi, VTlo,
                                              Opart, lpart);
    attn_merge_kernel<<<(NN * DD) / 256, 256, 0, stream>>>(Opart, lpart, HS, H,
                                                           Hhi, SQ);
    knn_kernel<<<KNSL * 64, 256, 0, stream>>>(Hhi, SQ, candV);
    knn_merge_kernel<<<NN / 64, 64, 0, stream>>>(candV, CAND);
    rerank_kernel<<<NN / 4, 256, 0, stream>>>(H, SQ, CAND, IDX);
    mat1_kernel<<<NN / 4, 128, 0, stream>>>(H, W1, M1);
    g1m2_kernel<<<NN, 128, 0, stream>>>(M1, IDX, b1, W2, M2);
    out_kernel<<<NN / 256, 256, 0, stream>>>(M2, IDX, b2, (float*)d_out);
}

// Round 12
// 447.712 us; speedup vs baseline: 1.7293x; 1.7293x over previous
//
#include <hip/hip_runtime.h>
#include <cmath>

// ---------------------------------------------------------------------------
// GraphTransformer on MI355X.  N=8192, D=128, k=7, OUT=1.
// Attention: split-bf16 (hi/lo) MFMA flash, fixed max (logits bounded).
//   QK^T MUST stay 3-term split (round-10: plain bf16 QK flips kNN).
//   NO register prefetch (round-8: spills).  launch_bounds MUST stay
//   (256,2): round-11's (256,3) capped VGPR at 84 -> spill storm
//   (FETCH 35->466GB).  VSTR/PSTR=34 shrinks LDS to 52.2KB; at VGPR=120
//   the LDS limit (3 blocks/CU) now governs occupancy - no cap needed.
// kNN: swapped-operand bf16 MFMA, per-lane register top-10 (u32-packed),
// in-kernel lq-merge -> candV, parallel final merge, exact fp32 re-rank.
// GCN tail: fp32 VALU, gather1+m2 fused.
// ---------------------------------------------------------------------------

typedef unsigned short ushort_t;

constexpr int   NN    = 8192;
constexpr int   DD    = 128;
constexpr int   KNB   = 7;
constexpr int   NL    = 10;              // per-lane kept candidates (knn)
constexpr int   NCAND = 12;              // merged candidates per node
constexpr float SCALE = 0.088388347648318447f;   // 1/sqrt(128)

using bf16x8 = __attribute__((ext_vector_type(8))) short;   // 8 bf16 = 4 VGPR
using f32x4  = __attribute__((ext_vector_type(4))) float;   // mfma acc

#define MFMA16(a, b, c) __builtin_amdgcn_mfma_f32_16x16x32_bf16((a), (b), (c), 0, 0, 0)

__device__ __forceinline__ ushort_t f2b(float f) {
    union { float f; unsigned int u; } v; v.f = f;
    return (ushort_t)((v.u + 0x8000u) >> 16);
}
__device__ __forceinline__ float b2f(ushort_t h) {
    union { unsigned int u; float f; } v; v.u = ((unsigned int)h) << 16;
    return v.f;
}

// u32 (d2-bits-truncated | idx13) top-K insert; valid because d2 > 0.
template<int K>
__device__ __forceinline__ void topk_insert_u32(unsigned* bk, unsigned key)
{
    if (key < bk[0]) {
        bool placed = false;
        #pragma unroll
        for (int p = 0; p < K - 1; ++p) {
            const unsigned nxt = bk[p + 1];
            const bool sh = (!placed) && (key < nxt);
            if (!placed) bk[p] = sh ? nxt : key;
            placed = placed || !sh;
        }
        if (!placed) bk[K - 1] = key;
    }
}

// ---------------- projections: Q,K (split bf16), V (f32), skip (f32) -------
__global__ __launch_bounds__(128)
void proj_kernel(const float* __restrict__ x,
                 const float* __restrict__ Wq, const float* __restrict__ bq,
                 const float* __restrict__ Wk, const float* __restrict__ bk,
                 const float* __restrict__ Wv, const float* __restrict__ bv,
                 const float* __restrict__ Ws, const float* __restrict__ bs,
                 ushort_t* __restrict__ Qhi, ushort_t* __restrict__ Qlo,
                 ushort_t* __restrict__ Khi, ushort_t* __restrict__ Klo,
                 float* __restrict__ Vf, float* __restrict__ HS)
{
    __shared__ float xs[4][DD];
    const int i0 = blockIdx.x * 4, t = threadIdx.x;
    #pragma unroll
    for (int r = 0; r < 4; ++r) xs[r][t] = x[(i0 + r) * DD + t];
    __syncthreads();
    float aq[4] = {0,0,0,0}, ak[4] = {0,0,0,0}, av[4] = {0,0,0,0}, ah[4] = {0,0,0,0};
    #pragma unroll 4
    for (int c = 0; c < DD; ++c) {
        const float wq = Wq[c * DD + t], wk = Wk[c * DD + t];
        const float wv = Wv[c * DD + t], ws = Ws[c * DD + t];
        #pragma unroll
        for (int r = 0; r < 4; ++r) {
            const float xv = xs[r][c];
            aq[r] = fmaf(xv, wq, aq[r]); ak[r] = fmaf(xv, wk, ak[r]);
            av[r] = fmaf(xv, wv, av[r]); ah[r] = fmaf(xv, ws, ah[r]);
        }
    }
    #pragma unroll
    for (int r = 0; r < 4; ++r) {
        const int o = (i0 + r) * DD + t;
        const float q = aq[r] + bq[t];
        const float k = ak[r] + bk[t];
        const ushort_t qh = f2b(q); Qhi[o] = qh; Qlo[o] = f2b(q - b2f(qh));
        const ushort_t kh = f2b(k); Khi[o] = kh; Klo[o] = f2b(k - b2f(kh));
        Vf[o] = av[r] + bv[t];
        HS[o] = ah[r] + bs[t];
    }
}

// ---------------- V transpose + split: VT{hi,lo}[f][n] = split(V[n][f]) ----
__global__ __launch_bounds__(256)
void vt_kernel(const float* __restrict__ Vf,
               ushort_t* __restrict__ VThi, ushort_t* __restrict__ VTlo)
{
    __shared__ float tile[64 * 132];
    const int k0 = blockIdx.x * 64, t = threadIdx.x;
    #pragma unroll
    for (int p = 0; p < 8; ++p) {
        const int slot = t + p * 256;        // 2048 slots: 64 rows x 32 f4-chunks
        const int r = slot >> 5, c4 = slot & 31;
        *reinterpret_cast<float4*>(&tile[r * 132 + c4 * 4]) =
            *reinterpret_cast<const float4*>(Vf + (k0 + r) * DD + c4 * 4);
    }
    __syncthreads();
    #pragma unroll
    for (int p = 0; p < 4; ++p) {
        const int slot = t + p * 256;        // 1024 slots: 128 feats x 8 chunks
        const int f = slot >> 3, kc = slot & 7;
        ushort_t hh[8], ll[8];
        #pragma unroll
        for (int i = 0; i < 8; ++i) {
            const float v = tile[(kc * 8 + i) * 132 + f];
            hh[i] = f2b(v); ll[i] = f2b(v - b2f(hh[i]));
        }
        *reinterpret_cast<uint4*>(VThi + f * NN + k0 + kc * 8) =
            *reinterpret_cast<const uint4*>(hh);
        *reinterpret_cast<uint4*>(VTlo + f * NN + k0 + kc * 8) =
            *reinterpret_cast<const uint4*>(ll);
    }
}

// ---------------- split-bf16 MFMA flash attention, fixed max ---------------
constexpr int ANS  = 8;                 // key slices
constexpr int AKS  = NN / ANS;          // 1024 keys per slice
constexpr int BK   = 32;                // keys per tile
constexpr int KSTR = 136;               // K row stride (bf16): <=2-way banks
constexpr int VSTR = 34;                // VT row stride (17 words, odd)
constexpr int PSTR = 34;

__global__ __launch_bounds__(256, 2)
void attn_kernel(const ushort_t* __restrict__ Qhi, const ushort_t* __restrict__ Qlo,
                 const ushort_t* __restrict__ Khg, const ushort_t* __restrict__ Klg,
                 const ushort_t* __restrict__ Vhg, const ushort_t* __restrict__ Vlg,
                 float* __restrict__ Opart, float* __restrict__ lpart)
{
    __shared__ __align__(16) ushort_t Khs[BK * KSTR];
    __shared__ __align__(16) ushort_t Kls[BK * KSTR];
    __shared__ __align__(16) ushort_t Vhs[128 * VSTR];
    __shared__ __align__(16) ushort_t Vls[128 * VSTR];
    __shared__ __align__(16) ushort_t Phs[4 * 32 * PSTR];
    __shared__ __align__(16) ushort_t Pls[4 * 32 * PSTR];

    const int t  = threadIdx.x;
    const int w  = t >> 6, l = t & 63;
    const int lc = l & 15, lq = l >> 4;
    const int b  = blockIdx.x;
    const int s  = b >> 6;              // slice 0..7
    const int qb = b & 63;
    const int i0 = qb * 128;
    const int k0 = s * AKS;
    ushort_t* Pwh = Phs + w * 32 * PSTR;
    ushort_t* Pwl = Pls + w * 32 * PSTR;

    bf16x8 qh[2][4], ql[2][4];
    #pragma unroll
    for (int sub = 0; sub < 2; ++sub) {
        const int row = i0 + w * 32 + sub * 16 + lc;
        #pragma unroll
        for (int kb = 0; kb < 4; ++kb) {
            qh[sub][kb] = *reinterpret_cast<const bf16x8*>(Qhi + row * DD + kb * 32 + lq * 8);
            ql[sub][kb] = *reinterpret_cast<const bf16x8*>(Qlo + row * DD + kb * 32 + lq * 8);
        }
    }

    const f32x4 zz = {0.f, 0.f, 0.f, 0.f};
    f32x4 oacc[2][8];
    #pragma unroll
    for (int sub = 0; sub < 2; ++sub)
        #pragma unroll
        for (int ft = 0; ft < 8; ++ft) oacc[sub][ft] = zz;
    float lrow[2][4];
    #pragma unroll
    for (int sub = 0; sub < 2; ++sub)
        #pragma unroll
        for (int r = 0; r < 4; ++r) lrow[sub][r] = 0.f;

    for (int jt0 = 0; jt0 < AKS; jt0 += BK) {
        const int jt = k0 + jt0;
        __syncthreads();
        #pragma unroll
        for (int p = 0; p < 2; ++p) {       // K tiles 32x128 (hi+lo)
            const int slot = t + p * 256;
            const int r = slot >> 4, c = slot & 15;
            *reinterpret_cast<uint4*>(&Khs[r * KSTR + c * 8]) =
                *reinterpret_cast<const uint4*>(Khg + (jt + r) * DD + c * 8);
            *reinterpret_cast<uint4*>(&Kls[r * KSTR + c * 8]) =
                *reinterpret_cast<const uint4*>(Klg + (jt + r) * DD + c * 8);
        }
        #pragma unroll
        for (int p = 0; p < 2; ++p) {       // VT tiles 128x32 (hi+lo)
            const int slot = t + p * 256;
            const int f = slot >> 2, c = slot & 3;
            *reinterpret_cast<uint4*>(&Vhs[f * VSTR + c * 8]) =
                *reinterpret_cast<const uint4*>(Vhg + f * NN + jt + c * 8);
            *reinterpret_cast<uint4*>(&Vls[f * VSTR + c * 8]) =
                *reinterpret_cast<const uint4*>(Vlg + f * NN + jt + c * 8);
        }
        __syncthreads();

        // ---- S = Q K^T, split: qh*kh + ql*kh + qh*kl ----
        f32x4 sacc[2][2];
        #pragma unroll
        for (int sub = 0; sub < 2; ++sub)
            #pragma unroll
            for (int ct = 0; ct < 2; ++ct) sacc[sub][ct] = zz;
        #pragma unroll
        for (int ct = 0; ct < 2; ++ct) {
            #pragma unroll
            for (int kb = 0; kb < 4; ++kb) {
                const bf16x8 kh = *reinterpret_cast<const bf16x8*>(
                    &Khs[(ct * 16 + lc) * KSTR + kb * 32 + lq * 8]);
                const bf16x8 kl = *reinterpret_cast<const bf16x8*>(
                    &Kls[(ct * 16 + lc) * KSTR + kb * 32 + lq * 8]);
                #pragma unroll
                for (int sub = 0; sub < 2; ++sub) {
                    sacc[sub][ct] = MFMA16(qh[sub][kb], kh, sacc[sub][ct]);
                    sacc[sub][ct] = MFMA16(ql[sub][kb], kh, sacc[sub][ct]);
                    sacc[sub][ct] = MFMA16(qh[sub][kb], kl, sacc[sub][ct]);
                }
            }
        }
        if ((jt & ~127) == i0) {            // diagonal mask
            #pragma unroll
            for (int sub = 0; sub < 2; ++sub)
                #pragma unroll
                for (int ct = 0; ct < 2; ++ct) {
                    const int gk = jt + ct * 16 + lc;
                    #pragma unroll
                    for (int r = 0; r < 4; ++r) {
                        const int gq = i0 + w * 32 + sub * 16 + lq * 4 + r;
                        if (gk == gq) sacc[sub][ct][r] = -INFINITY;
                    }
                }
        }
        // ---- P = exp(S*SCALE), split to LDS ----
        #pragma unroll
        for (int sub = 0; sub < 2; ++sub)
            #pragma unroll
            for (int ct = 0; ct < 2; ++ct)
                #pragma unroll
                for (int r = 0; r < 4; ++r) {
                    const float p = __expf(sacc[sub][ct][r] * SCALE);
                    lrow[sub][r] += p;
                    const ushort_t ph = f2b(p);
                    const int off = (sub * 16 + lq * 4 + r) * PSTR + ct * 16 + lc;
                    Pwh[off] = ph;
                    Pwl[off] = f2b(p - b2f(ph));
                }
        bf16x8 pfh[2], pfl[2];
        #pragma unroll
        for (int sub = 0; sub < 2; ++sub) {
            pfh[sub] = *reinterpret_cast<const bf16x8*>(&Pwh[(sub * 16 + lc) * PSTR + lq * 8]);
            pfl[sub] = *reinterpret_cast<const bf16x8*>(&Pwl[(sub * 16 + lc) * PSTR + lq * 8]);
        }
        // ---- O += P V, split: ph*vh + pl*vh + ph*vl ----
        #pragma unroll
        for (int ft = 0; ft < 8; ++ft) {
            const bf16x8 vh = *reinterpret_cast<const bf16x8*>(
                &Vhs[(ft * 16 + lc) * VSTR + lq * 8]);
            const bf16x8 vl = *reinterpret_cast<const bf16x8*>(
                &Vls[(ft * 16 + lc) * VSTR + lq * 8]);
            #pragma unroll
            for (int sub = 0; sub < 2; ++sub) {
                oacc[sub][ft] = MFMA16(pfh[sub], vh, oacc[sub][ft]);
                oacc[sub][ft] = MFMA16(pfl[sub], vh, oacc[sub][ft]);
                oacc[sub][ft] = MFMA16(pfh[sub], vl, oacc[sub][ft]);
            }
        }
    }

    #pragma unroll
    for (int sub = 0; sub < 2; ++sub) {
        #pragma unroll
        for (int r = 0; r < 4; ++r) {
            float ps = lrow[sub][r];
            ps += __shfl_xor(ps, 1, 64);
            ps += __shfl_xor(ps, 2, 64);
            ps += __shfl_xor(ps, 4, 64);
            ps += __shfl_xor(ps, 8, 64);
            lrow[sub][r] = ps;
        }
        #pragma unroll
        for (int r = 0; r < 4; ++r) {
            const int row = i0 + w * 32 + sub * 16 + lq * 4 + r;
            float* po = Opart + ((size_t)s * NN + row) * DD;
            #pragma unroll
            for (int ft = 0; ft < 8; ++ft) po[ft * 16 + lc] = oacc[sub][ft][r];
        }
        if (lc == 0) {
            #pragma unroll
            for (int r = 0; r < 4; ++r) {
                const int row = i0 + w * 32 + sub * 16 + lq * 4 + r;
                lpart[s * NN + row] = lrow[sub][r];
            }
        }
    }
}

// ------- merge slices + skip, emit H (in-place over HS), Hhi, SQ -----------
__global__ __launch_bounds__(256)
void attn_merge_kernel(const float* __restrict__ Opart, const float* __restrict__ lpart,
                       const float* __restrict__ HS, float* __restrict__ H,
                       ushort_t* __restrict__ Hhi, float* __restrict__ SQ)
{
    __shared__ float red[256];
    const int t = threadIdx.x;
    const int gid = blockIdx.x * 256 + t;
    const int i = gid >> 7, f = gid & 127;
    float ls = 0.f, o = 0.f;
    #pragma unroll
    for (int s = 0; s < ANS; ++s) {
        ls += lpart[s * NN + i];
        o  += Opart[((size_t)s * NN + i) * DD + f];
    }
    const float h = o / ls + HS[i * DD + f];
    H[i * DD + f]   = h;
    Hhi[i * DD + f] = f2b(h);
    red[t] = h * h;
    __syncthreads();
    for (int s2 = 64; s2 > 0; s2 >>= 1) {
        if ((t & 127) < s2) red[t] += red[t + s2];
        __syncthreads();
    }
    if ((t & 127) == 0) SQ[i] = red[t];
}

// ---------------- kNN: swapped-operand MFMA, register top-NL (u32) ---------
constexpr int KNSL = 16;                // key slices (512 keys each)
constexpr int KSL  = NN / KNSL;         // 512

__global__ __launch_bounds__(256, 4)
void knn_kernel(const ushort_t* __restrict__ Hhi, const float* __restrict__ SQg,
                unsigned* __restrict__ candV)
{
    __shared__ __align__(16) ushort_t Khi[64 * KSTR];
    __shared__ __align__(16) float sqs[64];

    const int t  = threadIdx.x;
    const int w  = t >> 6, l = t & 63;
    const int lc = l & 15, lq = l >> 4;
    const int b  = blockIdx.x;
    const int s  = b >> 6;              // slice 0..15
    const int qb = b & 63;
    const int i0 = qb * 128;
    const int k0 = s * KSL;

    const int kr = t >> 4, kc2 = t & 15;   // staging coords (4 chunks of 16 rows)

    const int gq0 = i0 + w * 32 + lc;          // sub=0 query
    const int gq1 = gq0 + 16;                  // sub=1 query
    const float sqi0 = SQg[gq0];
    const float sqi1 = SQg[gq1];

    bf16x8 qf[2][4];                    // B operand: B[n=query=lc][k=lq*8+j]
    #pragma unroll
    for (int sub = 0; sub < 2; ++sub) {
        const int row = i0 + w * 32 + sub * 16 + lc;
        #pragma unroll
        for (int kb = 0; kb < 4; ++kb)
            qf[sub][kb] = *reinterpret_cast<const bf16x8*>(Hhi + row * DD + kb * 32 + lq * 8);
    }

    unsigned lists[2][NL];
    #pragma unroll
    for (int sub = 0; sub < 2; ++sub)
        #pragma unroll
        for (int p = 0; p < NL; ++p) lists[sub][p] = 0xFFFFFFFFu;

    // prefetch tile 0 (knn has VGPR headroom, no spill at 4 waves/EU)
    uint4 pk[4]; float psq;
    #pragma unroll
    for (int p = 0; p < 4; ++p)
        pk[p] = *reinterpret_cast<const uint4*>(Hhi + (k0 + kr + p * 16) * DD + kc2 * 8);
    psq = (t < 64) ? SQg[k0 + t] : 0.f;

    const f32x4 zz = {0.f, 0.f, 0.f, 0.f};
    for (int jt0 = 0; jt0 < KSL; jt0 += 64) {
        const int jt = k0 + jt0;
        __syncthreads();                 // prev K-frag reads done
        #pragma unroll
        for (int p = 0; p < 4; ++p)
            *reinterpret_cast<uint4*>(&Khi[(kr + p * 16) * KSTR + kc2 * 8]) = pk[p];
        if (t < 64) sqs[t] = psq;
        __syncthreads();
        if (jt0 + 64 < KSL) {            // prefetch next during compute
            const int jn = jt + 64;
            #pragma unroll
            for (int p = 0; p < 4; ++p)
                pk[p] = *reinterpret_cast<const uint4*>(Hhi + (jn + kr + p * 16) * DD + kc2 * 8);
            psq = (t < 64) ? SQg[jn + t] : 0.f;
        }

        f32x4 acc[2][4];                 // [sub][kt]
        #pragma unroll
        for (int sub = 0; sub < 2; ++sub)
            #pragma unroll
            for (int kt = 0; kt < 4; ++kt) acc[sub][kt] = zz;
        #pragma unroll
        for (int kt = 0; kt < 4; ++kt) {
            #pragma unroll
            for (int kb = 0; kb < 4; ++kb) {
                const bf16x8 kf = *reinterpret_cast<const bf16x8*>(
                    &Khi[(kt * 16 + lc) * KSTR + kb * 32 + lq * 8]);
                acc[0][kt] = MFMA16(kf, qf[0][kb], acc[0][kt]);   // A=key, B=query
                acc[1][kt] = MFMA16(kf, qf[1][kb], acc[1][kt]);
            }
        }

        const bool ovl = ((jt & ~127) == i0);
        #pragma unroll
        for (int kt = 0; kt < 4; ++kt) {
            const float4 sq4 = *reinterpret_cast<const float4*>(&sqs[kt * 16 + lq * 4]);
            const float sqj[4] = {sq4.x, sq4.y, sq4.z, sq4.w};
            #pragma unroll
            for (int r = 0; r < 4; ++r) {
                const int gk = jt + kt * 16 + lq * 4 + r;
                float d0 = fmaf(-2.f, acc[0][kt][r], sqi0 + sqj[r]);
                float d1 = fmaf(-2.f, acc[1][kt][r], sqi1 + sqj[r]);
                if (ovl) {
                    if (gk == gq0) d0 = INFINITY;
                    if (gk == gq1) d1 = INFINITY;
                }
                const unsigned u0 = (__float_as_uint(d0) & 0xFFFFE000u) | (unsigned)gk;
                const unsigned u1 = (__float_as_uint(d1) & 0xFFFFE000u) | (unsigned)gk;
                topk_insert_u32<NL>(lists[0], u0);
                topk_insert_u32<NL>(lists[1], u1);
            }
        }
    }

    // ---- in-kernel lq-merge: Khi is dead, reuse as scratch ----
    __syncthreads();                     // all waves done with Khi MFMA reads
    unsigned* msw = reinterpret_cast<unsigned*>(Khi) + w * (16 * 4 * NL);
    #pragma unroll
    for (int sub = 0; sub < 2; ++sub) {
        #pragma unroll
        for (int p = 0; p < NL; ++p)
            msw[lc * (4 * NL) + lq * NL + p] = lists[sub][p];
        __syncthreads();
        if (lq == 0) {                   // 16 lanes/wave: one query each
            unsigned bk[NL];
            #pragma unroll
            for (int p = 0; p < NL; ++p) bk[p] = msw[lc * (4 * NL) + p];
            #pragma unroll
            for (int o = 1; o < 4; ++o)
                #pragma unroll
                for (int e = 0; e < NL; ++e)
                    topk_insert_u32<NL>(bk, msw[lc * (4 * NL) + o * NL + e]);
            const int node = i0 + w * 32 + sub * 16 + lc;
            #pragma unroll
            for (int p = 0; p < NL; ++p)
                candV[((size_t)s * NL + p) * NN + node] = bk[p];
        }
        __syncthreads();
    }
}

// ------- final merge: 16 slice lists -> top-12 candidates per node ---------
__global__ __launch_bounds__(64)
void knn_merge_kernel(const unsigned* __restrict__ candV, int* __restrict__ CAND)
{
    const int q = blockIdx.x * 64 + threadIdx.x;
    unsigned bk[NCAND];
    #pragma unroll
    for (int p = 0; p < NCAND; ++p) bk[p] = 0xFFFFFFFFu;
    for (int s = 0; s < KNSL; ++s)
        #pragma unroll
        for (int e = 0; e < NL; ++e)
            topk_insert_u32<NCAND>(bk, candV[((size_t)s * NL + e) * NN + q]);
    #pragma unroll
    for (int p = 0; p < NCAND; ++p)
        CAND[q * NCAND + p] = (int)(bk[p] & 8191u);
}

// ---------------- exact fp32 re-rank of candidates -> IDX ----------------
__global__ __launch_bounds__(256)
void rerank_kernel(const float* __restrict__ H, const float* __restrict__ SQ,
                   const int* __restrict__ CAND, int* __restrict__ IDX)
{
    const int t = threadIdx.x;
    const int w = t >> 6, l = t & 63;
    const int node = blockIdx.x * 4 + w;
    const float h0 = H[node * DD + l];
    const float h1 = H[node * DD + 64 + l];
    float dk[NCAND]; int di[NCAND];
    #pragma unroll
    for (int c = 0; c < NCAND; ++c) {
        const int j = CAND[node * NCAND + c];
        float p = h0 * H[j * DD + l] + h1 * H[j * DD + 64 + l];
        p += __shfl_xor(p, 1, 64);
        p += __shfl_xor(p, 2, 64);
        p += __shfl_xor(p, 4, 64);
        p += __shfl_xor(p, 8, 64);
        p += __shfl_xor(p, 16, 64);
        p += __shfl_xor(p, 32, 64);
        dk[c] = SQ[j] - 2.f * p;
        di[c] = j;
    }
    if (l == 0) {
        #pragma unroll
        for (int s = 0; s < KNB; ++s) {
            int best = s;
            #pragma unroll
            for (int c = s + 1; c < NCAND; ++c) {
                const bool lt = (dk[c] < dk[best]) ||
                                (dk[c] == dk[best] && di[c] < di[best]);
                if (lt) best = c;
            }
            const float tk = dk[s]; dk[s] = dk[best]; dk[best] = tk;
            const int   ti = di[s]; di[s] = di[best]; di[best] = ti;
            IDX[node * KNB + s] = di[s];
        }
    }
}

// ---------------- M1 = H @ W1 (f32, 4 rows/block) ----------------
__global__ __launch_bounds__(128)
void mat1_kernel(const float* __restrict__ Hin, const float* __restrict__ W,
                 float* __restrict__ M)
{
    __shared__ float xs[4][DD];
    const int i0 = blockIdx.x * 4, t = threadIdx.x;
    #pragma unroll
    for (int r = 0; r < 4; ++r) xs[r][t] = Hin[(i0 + r) * DD + t];
    __syncthreads();
    float a[4] = {0,0,0,0};
    #pragma unroll 4
    for (int c = 0; c < DD; ++c) {
        const float wv = W[c * DD + t];
        #pragma unroll
        for (int r = 0; r < 4; ++r) a[r] = fmaf(xs[r][c], wv, a[r]);
    }
    #pragma unroll
    for (int r = 0; r < 4; ++r) M[(i0 + r) * DD + t] = a[r];
}

// -------- fused: H1 = relu((sum_nbr M1 + M1)/8 + b1); M2 = H1.W2 ----------
__global__ __launch_bounds__(128)
void g1m2_kernel(const float* __restrict__ M1, const int* __restrict__ IDX,
                 const float* __restrict__ b1, const float* __restrict__ W2,
                 float* __restrict__ M2)
{
    __shared__ float red[128];
    const int i = blockIdx.x, t = threadIdx.x;
    float s = M1[i * DD + t];
    #pragma unroll
    for (int p = 0; p < KNB; ++p) s += M1[IDX[i * KNB + p] * DD + t];
    const float h1 = fmaxf(s * 0.125f + b1[t], 0.f);
    red[t] = h1 * W2[t];
    __syncthreads();
    for (int s2 = 64; s2 > 0; s2 >>= 1) {
        if (t < s2) red[t] += red[t + s2];
        __syncthreads();
    }
    if (t == 0) M2[i] = red[0];
}

// ---------------- out = (sum_nbr M2 + M2)/8 + b2 ----------------
__global__ __launch_bounds__(256)
void out_kernel(const float* __restrict__ M2, const int* __restrict__ IDX,
                const float* __restrict__ b2, float* __restrict__ out)
{
    const int i = blockIdx.x * 256 + threadIdx.x;
    if (i < NN) {
        float s = M2[i];
        #pragma unroll
        for (int p = 0; p < KNB; ++p) s += M2[IDX[i * KNB + p]];
        out[i] = s * 0.125f + b2[0];
    }
}

// ---------------------------------------------------------------------------
extern "C" void kernel_launch(void* const* d_in, const int* in_sizes, int n_in,
                              void* d_out, int out_size, void* d_ws, size_t ws_size,
                              hipStream_t stream)
{
    const float* x   = (const float*)d_in[0];
    const float* Wq  = (const float*)d_in[1];
    const float* bq  = (const float*)d_in[2];
    const float* Wk  = (const float*)d_in[3];
    const float* bk  = (const float*)d_in[4];
    const float* Wv  = (const float*)d_in[5];
    const float* bv  = (const float*)d_in[6];
    const float* Wsk = (const float*)d_in[7];
    const float* bsk = (const float*)d_in[8];
    const float* W1  = (const float*)d_in[9];
    const float* b1  = (const float*)d_in[10];
    const float* W2  = (const float*)d_in[11];
    const float* b2  = (const float*)d_in[12];

    constexpr size_t MB = 1024 * 1024;
    char* W = (char*)d_ws;
    // persistent: [0,8) Q/K splits, [8,12) VT splits, [12,16) HS (->H in place)
    ushort_t* Qhi  = (ushort_t*)(W + 0 * MB);
    ushort_t* Qlo  = (ushort_t*)(W + 2 * MB);
    ushort_t* Khi  = (ushort_t*)(W + 4 * MB);
    ushort_t* Klo  = (ushort_t*)(W + 6 * MB);
    ushort_t* VThi = (ushort_t*)(W + 8 * MB);
    ushort_t* VTlo = (ushort_t*)(W + 10 * MB);
    float*    HS   = (float*)(W + 12 * MB);
    float*    H    = HS;                                   // in-place merge
    ushort_t* Hhi  = Qhi;            // Q dead after attn; Hhi written by merge
    // small: [16,17)
    float* lpart = (float*)(W + 16 * MB);                  // 256KB
    float* SQ    = (float*)(W + 16 * MB + 256 * 1024);     // 32KB
    float* M2    = SQ + NN;                                // 32KB
    int*   IDX   = (int*)(M2 + NN);                        // 224KB
    // union: [17,49):
    //   Vf32  [17,21)   dead after vt
    //   Opart [17,49)   dead after attn_merge
    //   candV [17,22.25) written by knn, dead after knn_merge (5.25MB)
    //   CAND  [23,23.4) written by knn_merge, dead after rerank
    //   M1    [24,28)   written by mat1
    float*    Vf32  = (float*)(W + 17 * MB);
    float*    Opart = (float*)(W + 17 * MB);
    unsigned* candV = (unsigned*)(W + 17 * MB);
    int*      CAND  = (int*)(W + 23 * MB);
    float*    M1    = (float*)(W + 24 * MB);

    proj_kernel<<<NN / 4, 128, 0, stream>>>(x, Wq, bq, Wk, bk, Wv, bv, Wsk, bsk,
                                            Qhi, Qlo, Khi, Klo, Vf32, HS);
    vt_kernel<<<NN / 64, 256, 0, stream>>>(Vf32, VThi, VTlo);
    attn_kernel<<<ANS * 64, 256, 0, stream>>>(Qhi, Qlo, Khi, Klo, VThi, VTlo,
                                              Opart, lpart);
    attn_merge_kernel<<<(NN * DD) / 256, 256, 0, stream>>>(Opart, lpart, HS, H,
                                                           Hhi, SQ);
    knn_kernel<<<KNSL * 64, 256, 0, stream>>>(Hhi, SQ, candV);
    knn_merge_kernel<<<NN / 64, 64, 0, stream>>>(candV, CAND);
    rerank_kernel<<<NN / 4, 256, 0, stream>>>(H, SQ, CAND, IDX);
    mat1_kernel<<<NN / 4, 128, 0, stream>>>(H, W1, M1);
    g1m2_kernel<<<NN, 128, 0, stream>>>(M1, IDX, b1, W2, M2);
    out_kernel<<<NN / 256, 256, 0, stream>>>(M2, IDX, b2, (float*)d_out);
}

// Round 13
// 416.752 us; speedup vs baseline: 1.8577x; 1.0743x over previous
//
#include <hip/hip_runtime.h>
#include <cmath>

// ---------------------------------------------------------------------------
// GraphTransformer on MI355X.  N=8192, D=128, k=7, OUT=1.
// Attention: split-bf16 (hi/lo) MFMA flash, fixed max (logits bounded).
//   FROZEN config (every deviation regressed):
//   - QK^T 3-term split (round-10: plain bf16 QK flips kNN neighbors)
//   - NO register prefetch (round-8: scratch spills, WRITE 33->71MB)
//   - launch_bounds (256,2) (round-11: (256,3) caps VGPR at 84 -> spill storm)
//   - VSTR/PSTR=40 (round-12: 34 raised bank conflicts 1.15e7->1.89e7)
// kNN: swapped-operand bf16 MFMA, per-lane register top-10 (u32-packed),
// in-kernel lq-merge -> candV, parallel final merge, exact fp32 re-rank.
// attn_merge: float4-vectorized (this round's only change vs round 9).
// GCN tail: fp32 VALU, gather1+m2 fused.
// ---------------------------------------------------------------------------

typedef unsigned short ushort_t;

constexpr int   NN    = 8192;
constexpr int   DD    = 128;
constexpr int   KNB   = 7;
constexpr int   NL    = 10;              // per-lane kept candidates (knn)
constexpr int   NCAND = 12;              // merged candidates per node
constexpr float SCALE = 0.088388347648318447f;   // 1/sqrt(128)

using bf16x8 = __attribute__((ext_vector_type(8))) short;   // 8 bf16 = 4 VGPR
using f32x4  = __attribute__((ext_vector_type(4))) float;   // mfma acc

#define MFMA16(a, b, c) __builtin_amdgcn_mfma_f32_16x16x32_bf16((a), (b), (c), 0, 0, 0)

__device__ __forceinline__ ushort_t f2b(float f) {
    union { float f; unsigned int u; } v; v.f = f;
    return (ushort_t)((v.u + 0x8000u) >> 16);
}
__device__ __forceinline__ float b2f(ushort_t h) {
    union { unsigned int u; float f; } v; v.u = ((unsigned int)h) << 16;
    return v.f;
}

// u32 (d2-bits-truncated | idx13) top-K insert; valid because d2 > 0.
template<int K>
__device__ __forceinline__ void topk_insert_u32(unsigned* bk, unsigned key)
{
    if (key < bk[0]) {
        bool placed = false;
        #pragma unroll
        for (int p = 0; p < K - 1; ++p) {
            const unsigned nxt = bk[p + 1];
            const bool sh = (!placed) && (key < nxt);
            if (!placed) bk[p] = sh ? nxt : key;
            placed = placed || !sh;
        }
        if (!placed) bk[K - 1] = key;
    }
}

// ---------------- projections: Q,K (split bf16), V (f32), skip (f32) -------
__global__ __launch_bounds__(128)
void proj_kernel(const float* __restrict__ x,
                 const float* __restrict__ Wq, const float* __restrict__ bq,
                 const float* __restrict__ Wk, const float* __restrict__ bk,
                 const float* __restrict__ Wv, const float* __restrict__ bv,
                 const float* __restrict__ Ws, const float* __restrict__ bs,
                 ushort_t* __restrict__ Qhi, ushort_t* __restrict__ Qlo,
                 ushort_t* __restrict__ Khi, ushort_t* __restrict__ Klo,
                 float* __restrict__ Vf, float* __restrict__ HS)
{
    __shared__ float xs[4][DD];
    const int i0 = blockIdx.x * 4, t = threadIdx.x;
    #pragma unroll
    for (int r = 0; r < 4; ++r) xs[r][t] = x[(i0 + r) * DD + t];
    __syncthreads();
    float aq[4] = {0,0,0,0}, ak[4] = {0,0,0,0}, av[4] = {0,0,0,0}, ah[4] = {0,0,0,0};
    #pragma unroll 4
    for (int c = 0; c < DD; ++c) {
        const float wq = Wq[c * DD + t], wk = Wk[c * DD + t];
        const float wv = Wv[c * DD + t], ws = Ws[c * DD + t];
        #pragma unroll
        for (int r = 0; r < 4; ++r) {
            const float xv = xs[r][c];
            aq[r] = fmaf(xv, wq, aq[r]); ak[r] = fmaf(xv, wk, ak[r]);
            av[r] = fmaf(xv, wv, av[r]); ah[r] = fmaf(xv, ws, ah[r]);
        }
    }
    #pragma unroll
    for (int r = 0; r < 4; ++r) {
        const int o = (i0 + r) * DD + t;
        const float q = aq[r] + bq[t];
        const float k = ak[r] + bk[t];
        const ushort_t qh = f2b(q); Qhi[o] = qh; Qlo[o] = f2b(q - b2f(qh));
        const ushort_t kh = f2b(k); Khi[o] = kh; Klo[o] = f2b(k - b2f(kh));
        Vf[o] = av[r] + bv[t];
        HS[o] = ah[r] + bs[t];
    }
}

// ---------------- V transpose + split: VT{hi,lo}[f][n] = split(V[n][f]) ----
__global__ __launch_bounds__(256)
void vt_kernel(const float* __restrict__ Vf,
               ushort_t* __restrict__ VThi, ushort_t* __restrict__ VTlo)
{
    __shared__ float tile[64 * 132];
    const int k0 = blockIdx.x * 64, t = threadIdx.x;
    #pragma unroll
    for (int p = 0; p < 8; ++p) {
        const int slot = t + p * 256;        // 2048 slots: 64 rows x 32 f4-chunks
        const int r = slot >> 5, c4 = slot & 31;
        *reinterpret_cast<float4*>(&tile[r * 132 + c4 * 4]) =
            *reinterpret_cast<const float4*>(Vf + (k0 + r) * DD + c4 * 4);
    }
    __syncthreads();
    #pragma unroll
    for (int p = 0; p < 4; ++p) {
        const int slot = t + p * 256;        // 1024 slots: 128 feats x 8 chunks
        const int f = slot >> 3, kc = slot & 7;
        ushort_t hh[8], ll[8];
        #pragma unroll
        for (int i = 0; i < 8; ++i) {
            const float v = tile[(kc * 8 + i) * 132 + f];
            hh[i] = f2b(v); ll[i] = f2b(v - b2f(hh[i]));
        }
        *reinterpret_cast<uint4*>(VThi + f * NN + k0 + kc * 8) =
            *reinterpret_cast<const uint4*>(hh);
        *reinterpret_cast<uint4*>(VTlo + f * NN + k0 + kc * 8) =
            *reinterpret_cast<const uint4*>(ll);
    }
}

// ---------------- split-bf16 MFMA flash attention, fixed max ---------------
constexpr int ANS  = 8;                 // key slices
constexpr int AKS  = NN / ANS;          // 1024 keys per slice
constexpr int BK   = 32;                // keys per tile
constexpr int KSTR = 136;               // K row stride (bf16): <=2-way banks
constexpr int VSTR = 40;                // VT row stride (32+8) — proven
constexpr int PSTR = 40;

__global__ __launch_bounds__(256, 2)
void attn_kernel(const ushort_t* __restrict__ Qhi, const ushort_t* __restrict__ Qlo,
                 const ushort_t* __restrict__ Khg, const ushort_t* __restrict__ Klg,
                 const ushort_t* __restrict__ Vhg, const ushort_t* __restrict__ Vlg,
                 float* __restrict__ Opart, float* __restrict__ lpart)
{
    __shared__ __align__(16) ushort_t Khs[BK * KSTR];
    __shared__ __align__(16) ushort_t Kls[BK * KSTR];
    __shared__ __align__(16) ushort_t Vhs[128 * VSTR];
    __shared__ __align__(16) ushort_t Vls[128 * VSTR];
    __shared__ __align__(16) ushort_t Phs[4 * 32 * PSTR];
    __shared__ __align__(16) ushort_t Pls[4 * 32 * PSTR];

    const int t  = threadIdx.x;
    const int w  = t >> 6, l = t & 63;
    const int lc = l & 15, lq = l >> 4;
    const int b  = blockIdx.x;
    const int s  = b >> 6;              // slice 0..7
    const int qb = b & 63;
    const int i0 = qb * 128;
    const int k0 = s * AKS;
    ushort_t* Pwh = Phs + w * 32 * PSTR;
    ushort_t* Pwl = Pls + w * 32 * PSTR;

    bf16x8 qh[2][4], ql[2][4];
    #pragma unroll
    for (int sub = 0; sub < 2; ++sub) {
        const int row = i0 + w * 32 + sub * 16 + lc;
        #pragma unroll
        for (int kb = 0; kb < 4; ++kb) {
            qh[sub][kb] = *reinterpret_cast<const bf16x8*>(Qhi + row * DD + kb * 32 + lq * 8);
            ql[sub][kb] = *reinterpret_cast<const bf16x8*>(Qlo + row * DD + kb * 32 + lq * 8);
        }
    }

    const f32x4 zz = {0.f, 0.f, 0.f, 0.f};
    f32x4 oacc[2][8];
    #pragma unroll
    for (int sub = 0; sub < 2; ++sub)
        #pragma unroll
        for (int ft = 0; ft < 8; ++ft) oacc[sub][ft] = zz;
    float lrow[2][4];
    #pragma unroll
    for (int sub = 0; sub < 2; ++sub)
        #pragma unroll
        for (int r = 0; r < 4; ++r) lrow[sub][r] = 0.f;

    for (int jt0 = 0; jt0 < AKS; jt0 += BK) {
        const int jt = k0 + jt0;
        __syncthreads();
        #pragma unroll
        for (int p = 0; p < 2; ++p) {       // K tiles 32x128 (hi+lo)
            const int slot = t + p * 256;
            const int r = slot >> 4, c = slot & 15;
            *reinterpret_cast<uint4*>(&Khs[r * KSTR + c * 8]) =
                *reinterpret_cast<const uint4*>(Khg + (jt + r) * DD + c * 8);
            *reinterpret_cast<uint4*>(&Kls[r * KSTR + c * 8]) =
                *reinterpret_cast<const uint4*>(Klg + (jt + r) * DD + c * 8);
        }
        #pragma unroll
        for (int p = 0; p < 2; ++p) {       // VT tiles 128x32 (hi+lo)
            const int slot = t + p * 256;
            const int f = slot >> 2, c = slot & 3;
            *reinterpret_cast<uint4*>(&Vhs[f * VSTR + c * 8]) =
                *reinterpret_cast<const uint4*>(Vhg + f * NN + jt + c * 8);
            *reinterpret_cast<uint4*>(&Vls[f * VSTR + c * 8]) =
                *reinterpret_cast<const uint4*>(Vlg + f * NN + jt + c * 8);
        }
        __syncthreads();

        // ---- S = Q K^T, split: qh*kh + ql*kh + qh*kl ----
        f32x4 sacc[2][2];
        #pragma unroll
        for (int sub = 0; sub < 2; ++sub)
            #pragma unroll
            for (int ct = 0; ct < 2; ++ct) sacc[sub][ct] = zz;
        #pragma unroll
        for (int ct = 0; ct < 2; ++ct) {
            #pragma unroll
            for (int kb = 0; kb < 4; ++kb) {
                const bf16x8 kh = *reinterpret_cast<const bf16x8*>(
                    &Khs[(ct * 16 + lc) * KSTR + kb * 32 + lq * 8]);
                const bf16x8 kl = *reinterpret_cast<const bf16x8*>(
                    &Kls[(ct * 16 + lc) * KSTR + kb * 32 + lq * 8]);
                #pragma unroll
                for (int sub = 0; sub < 2; ++sub) {
                    sacc[sub][ct] = MFMA16(qh[sub][kb], kh, sacc[sub][ct]);
                    sacc[sub][ct] = MFMA16(ql[sub][kb], kh, sacc[sub][ct]);
                    sacc[sub][ct] = MFMA16(qh[sub][kb], kl, sacc[sub][ct]);
                }
            }
        }
        if ((jt & ~127) == i0) {            // diagonal mask
            #pragma unroll
            for (int sub = 0; sub < 2; ++sub)
                #pragma unroll
                for (int ct = 0; ct < 2; ++ct) {
                    const int gk = jt + ct * 16 + lc;
                    #pragma unroll
                    for (int r = 0; r < 4; ++r) {
                        const int gq = i0 + w * 32 + sub * 16 + lq * 4 + r;
                        if (gk == gq) sacc[sub][ct][r] = -INFINITY;
                    }
                }
        }
        // ---- P = exp(S*SCALE), split to LDS ----
        #pragma unroll
        for (int sub = 0; sub < 2; ++sub)
            #pragma unroll
            for (int ct = 0; ct < 2; ++ct)
                #pragma unroll
                for (int r = 0; r < 4; ++r) {
                    const float p = __expf(sacc[sub][ct][r] * SCALE);
                    lrow[sub][r] += p;
                    const ushort_t ph = f2b(p);
                    const int off = (sub * 16 + lq * 4 + r) * PSTR + ct * 16 + lc;
                    Pwh[off] = ph;
                    Pwl[off] = f2b(p - b2f(ph));
                }
        bf16x8 pfh[2], pfl[2];
        #pragma unroll
        for (int sub = 0; sub < 2; ++sub) {
            pfh[sub] = *reinterpret_cast<const bf16x8*>(&Pwh[(sub * 16 + lc) * PSTR + lq * 8]);
            pfl[sub] = *reinterpret_cast<const bf16x8*>(&Pwl[(sub * 16 + lc) * PSTR + lq * 8]);
        }
        // ---- O += P V, split: ph*vh + pl*vh + ph*vl ----
        #pragma unroll
        for (int ft = 0; ft < 8; ++ft) {
            const bf16x8 vh = *reinterpret_cast<const bf16x8*>(
                &Vhs[(ft * 16 + lc) * VSTR + lq * 8]);
            const bf16x8 vl = *reinterpret_cast<const bf16x8*>(
                &Vls[(ft * 16 + lc) * VSTR + lq * 8]);
            #pragma unroll
            for (int sub = 0; sub < 2; ++sub) {
                oacc[sub][ft] = MFMA16(pfh[sub], vh, oacc[sub][ft]);
                oacc[sub][ft] = MFMA16(pfl[sub], vh, oacc[sub][ft]);
                oacc[sub][ft] = MFMA16(pfh[sub], vl, oacc[sub][ft]);
            }
        }
    }

    #pragma unroll
    for (int sub = 0; sub < 2; ++sub) {
        #pragma unroll
        for (int r = 0; r < 4; ++r) {
            float ps = lrow[sub][r];
            ps += __shfl_xor(ps, 1, 64);
            ps += __shfl_xor(ps, 2, 64);
            ps += __shfl_xor(ps, 4, 64);
            ps += __shfl_xor(ps, 8, 64);
            lrow[sub][r] = ps;
        }
        #pragma unroll
        for (int r = 0; r < 4; ++r) {
            const int row = i0 + w * 32 + sub * 16 + lq * 4 + r;
            float* po = Opart + ((size_t)s * NN + row) * DD;
            #pragma unroll
            for (int ft = 0; ft < 8; ++ft) po[ft * 16 + lc] = oacc[sub][ft][r];
        }
        if (lc == 0) {
            #pragma unroll
            for (int r = 0; r < 4; ++r) {
                const int row = i0 + w * 32 + sub * 16 + lq * 4 + r;
                lpart[s * NN + row] = lrow[sub][r];
            }
        }
    }
}

// ------- merge slices + skip, emit H (in-place over HS), Hhi, SQ -----------
// float4-vectorized: 32 threads per node, 4 features per thread.
__global__ __launch_bounds__(256)
void attn_merge_kernel(const float* __restrict__ Opart, const float* __restrict__ lpart,
                       const float* __restrict__ HS, float* __restrict__ H,
                       ushort_t* __restrict__ Hhi, float* __restrict__ SQ)
{
    const int t = threadIdx.x;
    const int gid = blockIdx.x * 256 + t;
    const int i = gid >> 5;             // node
    const int f = (gid & 31) * 4;       // feature quad
    float ls = 0.f;
    float4 o = {0.f, 0.f, 0.f, 0.f};
    #pragma unroll
    for (int s = 0; s < ANS; ++s) {
        ls += lpart[s * NN + i];
        const float4 ov = *reinterpret_cast<const float4*>(
            Opart + ((size_t)s * NN + i) * DD + f);
        o.x += ov.x; o.y += ov.y; o.z += ov.z; o.w += ov.w;
    }
    const float4 hs = *reinterpret_cast<const float4*>(HS + i * DD + f);
    const float inv = 1.f / ls;
    float4 h;
    h.x = o.x * inv + hs.x; h.y = o.y * inv + hs.y;
    h.z = o.z * inv + hs.z; h.w = o.w * inv + hs.w;
    *reinterpret_cast<float4*>(H + i * DD + f) = h;
    ushort_t hb[4] = {f2b(h.x), f2b(h.y), f2b(h.z), f2b(h.w)};
    *reinterpret_cast<uint2*>(Hhi + i * DD + f) = *reinterpret_cast<const uint2*>(hb);
    float sq = h.x * h.x + h.y * h.y + h.z * h.z + h.w * h.w;
    sq += __shfl_xor(sq, 1, 64);
    sq += __shfl_xor(sq, 2, 64);
    sq += __shfl_xor(sq, 4, 64);
    sq += __shfl_xor(sq, 8, 64);
    sq += __shfl_xor(sq, 16, 64);       // xor<32 stays within the 32-lane node group
    if ((t & 31) == 0) SQ[i] = sq;
}

// ---------------- kNN: swapped-operand MFMA, register top-NL (u32) ---------
constexpr int KNSL = 16;                // key slices (512 keys each)
constexpr int KSL  = NN / KNSL;         // 512

__global__ __launch_bounds__(256, 4)
void knn_kernel(const ushort_t* __restrict__ Hhi, const float* __restrict__ SQg,
                unsigned* __restrict__ candV)
{
    __shared__ __align__(16) ushort_t Khi[64 * KSTR];
    __shared__ __align__(16) float sqs[64];

    const int t  = threadIdx.x;
    const int w  = t >> 6, l = t & 63;
    const int lc = l & 15, lq = l >> 4;
    const int b  = blockIdx.x;
    const int s  = b >> 6;              // slice 0..15
    const int qb = b & 63;
    const int i0 = qb * 128;
    const int k0 = s * KSL;

    const int kr = t >> 4, kc2 = t & 15;   // staging coords (4 chunks of 16 rows)

    const int gq0 = i0 + w * 32 + lc;          // sub=0 query
    const int gq1 = gq0 + 16;                  // sub=1 query
    const float sqi0 = SQg[gq0];
    const float sqi1 = SQg[gq1];

    bf16x8 qf[2][4];                    // B operand: B[n=query=lc][k=lq*8+j]
    #pragma unroll
    for (int sub = 0; sub < 2; ++sub) {
        const int row = i0 + w * 32 + sub * 16 + lc;
        #pragma unroll
        for (int kb = 0; kb < 4; ++kb)
            qf[sub][kb] = *reinterpret_cast<const bf16x8*>(Hhi + row * DD + kb * 32 + lq * 8);
    }

    unsigned lists[2][NL];
    #pragma unroll
    for (int sub = 0; sub < 2; ++sub)
        #pragma unroll
        for (int p = 0; p < NL; ++p) lists[sub][p] = 0xFFFFFFFFu;

    // prefetch tile 0 (knn has VGPR headroom, no spill at 4 waves/EU)
    uint4 pk[4]; float psq;
    #pragma unroll
    for (int p = 0; p < 4; ++p)
        pk[p] = *reinterpret_cast<const uint4*>(Hhi + (k0 + kr + p * 16) * DD + kc2 * 8);
    psq = (t < 64) ? SQg[k0 + t] : 0.f;

    const f32x4 zz = {0.f, 0.f, 0.f, 0.f};
    for (int jt0 = 0; jt0 < KSL; jt0 += 64) {
        const int jt = k0 + jt0;
        __syncthreads();                 // prev K-frag reads done
        #pragma unroll
        for (int p = 0; p < 4; ++p)
            *reinterpret_cast<uint4*>(&Khi[(kr + p * 16) * KSTR + kc2 * 8]) = pk[p];
        if (t < 64) sqs[t] = psq;
        __syncthreads();
        if (jt0 + 64 < KSL) {            // prefetch next during compute
            const int jn = jt + 64;
            #pragma unroll
            for (int p = 0; p < 4; ++p)
                pk[p] = *reinterpret_cast<const uint4*>(Hhi + (jn + kr + p * 16) * DD + kc2 * 8);
            psq = (t < 64) ? SQg[jn + t] : 0.f;
        }

        f32x4 acc[2][4];                 // [sub][kt]
        #pragma unroll
        for (int sub = 0; sub < 2; ++sub)
            #pragma unroll
            for (int kt = 0; kt < 4; ++kt) acc[sub][kt] = zz;
        #pragma unroll
        for (int kt = 0; kt < 4; ++kt) {
            #pragma unroll
            for (int kb = 0; kb < 4; ++kb) {
                const bf16x8 kf = *reinterpret_cast<const bf16x8*>(
                    &Khi[(kt * 16 + lc) * KSTR + kb * 32 + lq * 8]);
                acc[0][kt] = MFMA16(kf, qf[0][kb], acc[0][kt]);   // A=key, B=query
                acc[1][kt] = MFMA16(kf, qf[1][kb], acc[1][kt]);
            }
        }

        const bool ovl = ((jt & ~127) == i0);
        #pragma unroll
        for (int kt = 0; kt < 4; ++kt) {
            const float4 sq4 = *reinterpret_cast<const float4*>(&sqs[kt * 16 + lq * 4]);
            const float sqj[4] = {sq4.x, sq4.y, sq4.z, sq4.w};
            #pragma unroll
            for (int r = 0; r < 4; ++r) {
                const int gk = jt + kt * 16 + lq * 4 + r;
                float d0 = fmaf(-2.f, acc[0][kt][r], sqi0 + sqj[r]);
                float d1 = fmaf(-2.f, acc[1][kt][r], sqi1 + sqj[r]);
                if (ovl) {
                    if (gk == gq0) d0 = INFINITY;
                    if (gk == gq1) d1 = INFINITY;
                }
                const unsigned u0 = (__float_as_uint(d0) & 0xFFFFE000u) | (unsigned)gk;
                const unsigned u1 = (__float_as_uint(d1) & 0xFFFFE000u) | (unsigned)gk;
                topk_insert_u32<NL>(lists[0], u0);
                topk_insert_u32<NL>(lists[1], u1);
            }
        }
    }

    // ---- in-kernel lq-merge: Khi is dead, reuse as scratch ----
    __syncthreads();                     // all waves done with Khi MFMA reads
    unsigned* msw = reinterpret_cast<unsigned*>(Khi) + w * (16 * 4 * NL);
    #pragma unroll
    for (int sub = 0; sub < 2; ++sub) {
        #pragma unroll
        for (int p = 0; p < NL; ++p)
            msw[lc * (4 * NL) + lq * NL + p] = lists[sub][p];
        __syncthreads();
        if (lq == 0) {                   // 16 lanes/wave: one query each
            unsigned bk[NL];
            #pragma unroll
            for (int p = 0; p < NL; ++p) bk[p] = msw[lc * (4 * NL) + p];
            #pragma unroll
            for (int o = 1; o < 4; ++o)
                #pragma unroll
                for (int e = 0; e < NL; ++e)
                    topk_insert_u32<NL>(bk, msw[lc * (4 * NL) + o * NL + e]);
            const int node = i0 + w * 32 + sub * 16 + lc;
            #pragma unroll
            for (int p = 0; p < NL; ++p)
                candV[((size_t)s * NL + p) * NN + node] = bk[p];
        }
        __syncthreads();
    }
}

// ------- final merge: 16 slice lists -> top-12 candidates per node ---------
__global__ __launch_bounds__(64)
void knn_merge_kernel(const unsigned* __restrict__ candV, int* __restrict__ CAND)
{
    const int q = blockIdx.x * 64 + threadIdx.x;
    unsigned bk[NCAND];
    #pragma unroll
    for (int p = 0; p < NCAND; ++p) bk[p] = 0xFFFFFFFFu;
    for (int s = 0; s < KNSL; ++s)
        #pragma unroll
        for (int e = 0; e < NL; ++e)
            topk_insert_u32<NCAND>(bk, candV[((size_t)s * NL + e) * NN + q]);
    #pragma unroll
    for (int p = 0; p < NCAND; ++p)
        CAND[q * NCAND + p] = (int)(bk[p] & 8191u);
}

// ---------------- exact fp32 re-rank of candidates -> IDX ----------------
__global__ __launch_bounds__(256)
void rerank_kernel(const float* __restrict__ H, const float* __restrict__ SQ,
                   const int* __restrict__ CAND, int* __restrict__ IDX)
{
    const int t = threadIdx.x;
    const int w = t >> 6, l = t & 63;
    const int node = blockIdx.x * 4 + w;
    const float h0 = H[node * DD + l];
    const float h1 = H[node * DD + 64 + l];
    float dk[NCAND]; int di[NCAND];
    #pragma unroll
    for (int c = 0; c < NCAND; ++c) {
        const int j = CAND[node * NCAND + c];
        float p = h0 * H[j * DD + l] + h1 * H[j * DD + 64 + l];
        p += __shfl_xor(p, 1, 64);
        p += __shfl_xor(p, 2, 64);
        p += __shfl_xor(p, 4, 64);
        p += __shfl_xor(p, 8, 64);
        p += __shfl_xor(p, 16, 64);
        p += __shfl_xor(p, 32, 64);
        dk[c] = SQ[j] - 2.f * p;
        di[c] = j;
    }
    if (l == 0) {
        #pragma unroll
        for (int s = 0; s < KNB; ++s) {
            int best = s;
            #pragma unroll
            for (int c = s + 1; c < NCAND; ++c) {
                const bool lt = (dk[c] < dk[best]) ||
                                (dk[c] == dk[best] && di[c] < di[best]);
                if (lt) best = c;
            }
            const float tk = dk[s]; dk[s] = dk[best]; dk[best] = tk;
            const int   ti = di[s]; di[s] = di[best]; di[best] = ti;
            IDX[node * KNB + s] = di[s];
        }
    }
}

// ---------------- M1 = H @ W1 (f32, 4 rows/block) ----------------
__global__ __launch_bounds__(128)
void mat1_kernel(const float* __restrict__ Hin, const float* __restrict__ W,
                 float* __restrict__ M)
{
    __shared__ float xs[4][DD];
    const int i0 = blockIdx.x * 4, t = threadIdx.x;
    #pragma unroll
    for (int r = 0; r < 4; ++r) xs[r][t] = Hin[(i0 + r) * DD + t];
    __syncthreads();
    float a[4] = {0,0,0,0};
    #pragma unroll 4
    for (int c = 0; c < DD; ++c) {
        const float wv = W[c * DD + t];
        #pragma unroll
        for (int r = 0; r < 4; ++r) a[r] = fmaf(xs[r][c], wv, a[r]);
    }
    #pragma unroll
    for (int r = 0; r < 4; ++r) M[(i0 + r) * DD + t] = a[r];
}

// -------- fused: H1 = relu((sum_nbr M1 + M1)/8 + b1); M2 = H1.W2 ----------
__global__ __launch_bounds__(128)
void g1m2_kernel(const float* __restrict__ M1, const int* __restrict__ IDX,
                 const float* __restrict__ b1, const float* __restrict__ W2,
                 float* __restrict__ M2)
{
    __shared__ float red[128];
    const int i = blockIdx.x, t = threadIdx.x;
    float s = M1[i * DD + t];
    #pragma unroll
    for (int p = 0; p < KNB; ++p) s += M1[IDX[i * KNB + p] * DD + t];
    const float h1 = fmaxf(s * 0.125f + b1[t], 0.f);
    red[t] = h1 * W2[t];
    __syncthreads();
    for (int s2 = 64; s2 > 0; s2 >>= 1) {
        if (t < s2) red[t] += red[t + s2];
        __syncthreads();
    }
    if (t == 0) M2[i] = red[0];
}

// ---------------- out = (sum_nbr M2 + M2)/8 + b2 ----------------
__global__ __launch_bounds__(256)
void out_kernel(const float* __restrict__ M2, const int* __restrict__ IDX,
                const float* __restrict__ b2, float* __restrict__ out)
{
    const int i = blockIdx.x * 256 + threadIdx.x;
    if (i < NN) {
        float s = M2[i];
        #pragma unroll
        for (int p = 0; p < KNB; ++p) s += M2[IDX[i * KNB + p]];
        out[i] = s * 0.125f + b2[0];
    }
}

// ---------------------------------------------------------------------------
extern "C" void kernel_launch(void* const* d_in, const int* in_sizes, int n_in,
                              void* d_out, int out_size, void* d_ws, size_t ws_size,
                              hipStream_t stream)
{
    const float* x   = (const float*)d_in[0];
    const float* Wq  = (const float*)d_in[1];
    const float* bq  = (const float*)d_in[2];
    const float* Wk  = (const float*)d_in[3];
    const float* bk  = (const float*)d_in[4];
    const float* Wv  = (const float*)d_in[5];
    const float* bv  = (const float*)d_in[6];
    const float* Wsk = (const float*)d_in[7];
    const float* bsk = (const float*)d_in[8];
    const float* W1  = (const float*)d_in[9];
    const float* b1  = (const float*)d_in[10];
    const float* W2  = (const float*)d_in[11];
    const float* b2  = (const float*)d_in[12];

    constexpr size_t MB = 1024 * 1024;
    char* W = (char*)d_ws;
    // persistent: [0,8) Q/K splits, [8,12) VT splits, [12,16) HS (->H in place)
    ushort_t* Qhi  = (ushort_t*)(W + 0 * MB);
    ushort_t* Qlo  = (ushort_t*)(W + 2 * MB);
    ushort_t* Khi  = (ushort_t*)(W + 4 * MB);
    ushort_t* Klo  = (ushort_t*)(W + 6 * MB);
    ushort_t* VThi = (ushort_t*)(W + 8 * MB);
    ushort_t* VTlo = (ushort_t*)(W + 10 * MB);
    float*    HS   = (float*)(W + 12 * MB);
    float*    H    = HS;                                   // in-place merge
    ushort_t* Hhi  = Qhi;            // Q dead after attn; Hhi written by merge
    // small: [16,17)
    float* lpart = (float*)(W + 16 * MB);                  // 256KB
    float* SQ    = (float*)(W + 16 * MB + 256 * 1024);     // 32KB
    float* M2    = SQ + NN;                                // 32KB
    int*   IDX   = (int*)(M2 + NN);                        // 224KB
    // union: [17,49):
    //   Vf32  [17,21)   dead after vt
    //   Opart [17,49)   dead after attn_merge
    //   candV [17,22.25) written by knn, dead after knn_merge (5.25MB)
    //   CAND  [23,23.4) written by knn_merge, dead after rerank
    //   M1    [24,28)   written by mat1
    float*    Vf32  = (float*)(W + 17 * MB);
    float*    Opart = (float*)(W + 17 * MB);
    unsigned* candV = (unsigned*)(W + 17 * MB);
    int*      CAND  = (int*)(W + 23 * MB);
    float*    M1    = (float*)(W + 24 * MB);

    proj_kernel<<<NN / 4, 128, 0, stream>>>(x, Wq, bq, Wk, bk, Wv, bv, Wsk, bsk,
                                            Qhi, Qlo, Khi, Klo, Vf32, HS);
    vt_kernel<<<NN / 64, 256, 0, stream>>>(Vf32, VThi, VTlo);
    attn_kernel<<<ANS * 64, 256, 0, stream>>>(Qhi, Qlo, Khi, Klo, VThi, VTlo,
                                              Opart, lpart);
    attn_merge_kernel<<<(NN * 32) / 256, 256, 0, stream>>>(Opart, lpart, HS, H,
                                                           Hhi, SQ);
    knn_kernel<<<KNSL * 64, 256, 0, stream>>>(Hhi, SQ, candV);
    knn_merge_kernel<<<NN / 64, 64, 0, stream>>>(candV, CAND);
    rerank_kernel<<<NN / 4, 256, 0, stream>>>(H, SQ, CAND, IDX);
    mat1_kernel<<<NN / 4, 128, 0, stream>>>(H, W1, M1);
    g1m2_kernel<<<NN, 128, 0, stream>>>(M1, IDX, b1, W2, M2);
    out_kernel<<<NN / 256, 256, 0, stream>>>(M2, IDX, b2, (float*)d_out);
}